// Round 3
// baseline (320.755 us; speedup 1.0000x reference)
//
#include <hip/hip_runtime.h>

// RingAttention: out = softmax(Q K^T) V (no scale), B=32 SQ=1024 SKV=8192 D=64, fp32 I/O.
// R9: full-residency fix. R8 measured: 141.7us, MfmaUtil 21, VALUBusy 45, Occ 26%.
// Model closes at ~45% VALU-issue + ~55% dep-chain stall with only 3 blocks/CU resident
// and grid=4 blocks/CU -> 4th block is a serial ~33% tail.
//  - __launch_bounds__(256, 4): 4 blocks/CU (LDS 147/160 KB, VGPR 76<=128) -> no tail,
//    4th wave/SIMD fills stall slots, 8 qb-sharers of each K/V slice fully concurrent
//    (better L2 window; FETCH was 2.3x unique).
//  - ternary max-reduce chains -> v_max3_f32 fusion (T17).
// Carried from R8: lgkmcnt-only raw barriers (no vmcnt drain), 2-barrier tile with
// V-stage/prefetch overlapped under QK+softmax, tree reductions, setprio around MFMA.
// Carried from R6: NSPLIT=4 split-K, register prefetch, single-fp16 Q, permlane32_swap
// P exchange, conflict-free V^T staging, dbuf LDS, fp16 MFMA 32x32x16 S^T formulation.

#define NBATCH 32
#define SQL 1024
#define SKVL 8192
#define DH 64
#define BM 128                 // q rows per block (4 waves x 32)
#define BN 64                  // kv rows per tile
#define KSTR 72                // K lds row stride in halfs
#define VSTR 72                // V^T lds row stride in halfs (36 dwords: b128 reads phase-optimal)

typedef _Float16 half8 __attribute__((ext_vector_type(8)));
typedef __fp16 fp16x2 __attribute__((ext_vector_type(2)));
typedef float floatx16 __attribute__((ext_vector_type(16)));
typedef float floatx4 __attribute__((ext_vector_type(4)));
typedef unsigned int uint4v __attribute__((ext_vector_type(4)));
typedef unsigned int uint2v __attribute__((ext_vector_type(2)));

union F8U { uint4v u; half8 h; };

#if __has_builtin(__builtin_amdgcn_exp2f)
#define EXP2F(x) __builtin_amdgcn_exp2f(x)
#else
#define EXP2F(x) exp2f(x)
#endif

// __syncthreads minus the vmcnt drain: wait own LDS ops, barrier, fence reordering.
#define WGBAR() do {                                        \
    asm volatile("s_waitcnt lgkmcnt(0)" ::: "memory");      \
    __builtin_amdgcn_s_barrier();                           \
    asm volatile("" ::: "memory");                          \
  } while (0)

static __device__ __forceinline__ unsigned pk2(float a, float b) {
#if __has_builtin(__builtin_amdgcn_cvt_pkrtz)
  fp16x2 h = __builtin_amdgcn_cvt_pkrtz(a, b);
  return __builtin_bit_cast(unsigned, h);
#else
  union { _Float16 h[2]; unsigned u; } r;
  r.h[0] = (_Float16)a; r.h[1] = (_Float16)b; return r.u;
#endif
}

#if __has_builtin(__builtin_amdgcn_permlane32_swap)
#define HAVE_PL32 1
// a' = [a.lo | b.lo], b' = [a.hi | b.hi]  (one VALU instr, both results)
static __device__ __forceinline__ void pl32(unsigned& a, unsigned& b) {
  uint2v r = __builtin_amdgcn_permlane32_swap(a, b, false, false);
  a = r[0]; b = r[1];
}
#else
#define HAVE_PL32 0
#endif

template<int NSPLIT>
__global__ __launch_bounds__(256, 4)
void ring_attn(const float* __restrict__ q, const float* __restrict__ k,
               const float* __restrict__ v, float* __restrict__ out,
               float* __restrict__ pO, float* __restrict__ pM, float* __restrict__ pL)
{
  constexpr int NT = SKVL / NSPLIT / BN;   // tiles per block
  __shared__ _Float16 Kl[2][BN * KSTR];
  __shared__ _Float16 Vt[2][DH * VSTR];

  const int tid  = threadIdx.x;
  const int lane = tid & 63;
  const int wv   = tid >> 6;
  const int l31  = lane & 31;
  const int hb   = lane >> 5;
  const int b8   = hb * 8;

  int split, batch, qb;
  if (NSPLIT == 4) {                 // bi = qb*128 + batch*4 + split
    split = blockIdx.x & 3;          // all 8 qb-sharers of a K/V slice -> same XCD
    batch = (blockIdx.x >> 2) & 31;
    qb    = blockIdx.x >> 7;
  } else {
    split = 0;
    batch = blockIdx.x & 31;
    qb    = blockIdx.x >> 5;
  }

  const float* kp = k + ((size_t)batch * SKVL + (size_t)split * (SKVL / NSPLIT)) * DH;
  const float* vp = v + ((size_t)batch * SKVL + (size_t)split * (SKVL / NSPLIT)) * DH;

  // ---- Q: scale by log2(e), round to fp16 (B-operand frags: n=q=l31, k=d) ----
  const float* qp = q + ((size_t)batch * SQL + qb * BM + wv * 32 + l31) * DH;
  half8 qf[4];
#pragma unroll
  for (int kt = 0; kt < 4; ++kt) {
    float4 a = *(const float4*)(qp + kt * 16 + b8);
    float4 c = *(const float4*)(qp + kt * 16 + b8 + 4);
    float xs[8] = {a.x, a.y, a.z, a.w, c.x, c.y, c.z, c.w};
#pragma unroll
    for (int j = 0; j < 8; ++j)
      qf[kt][j] = (_Float16)(xs[j] * 1.44269504088896340736f);
  }

  // K staging: thread -> row krt(+16*it), cols kc..kc+3 (fp32)
  const int krt = tid >> 4;
  const int kc  = (tid & 15) * 4;
  // V staging (n-major, conflict-free): thread -> rows vnr,vnr+1, cols vcg..vcg+7
  const int vnr = 2 * (tid & 31);
  const int vcg = 8 * (tid >> 5);

  float4 gk[4], ga0, ga1, gb0, gb1;
  // prefetch tile 0
#pragma unroll
  for (int it = 0; it < 4; ++it)
    gk[it] = *(const float4*)(kp + (size_t)(krt + it * 16) * DH + kc);
  ga0 = *(const float4*)(vp + (size_t)vnr * DH + vcg);
  ga1 = *(const float4*)(vp + (size_t)vnr * DH + vcg + 4);
  gb0 = *(const float4*)(vp + (size_t)(vnr + 1) * DH + vcg);
  gb1 = *(const float4*)(vp + (size_t)(vnr + 1) * DH + vcg + 4);

  floatx16 accO[2];
#pragma unroll
  for (int i = 0; i < 2; ++i)
#pragma unroll
    for (int r = 0; r < 16; ++r) accO[i][r] = 0.f;
  float m_run = -3.0e38f, l_run = 0.f;

  int buf = 0;
  for (int tile = 0; tile < NT; ++tile) {
    _Float16* Kb = Kl[buf];
    _Float16* Vb = Vt[buf];

    // ---- stage K regs -> LDS[buf] (vmcnt for gk auto-counted by compiler) ----
#pragma unroll
    for (int it = 0; it < 4; ++it) {
      uint2 w2 = make_uint2(pk2(gk[it].x, gk[it].y), pk2(gk[it].z, gk[it].w));
      *(uint2*)&Kb[(krt + it * 16) * KSTR + kc] = w2;
    }
    WGBAR();                         // B1: K visible; V loads still in flight

    // ---- stage V regs -> LDS[buf] (overlaps QK below; compiler schedules) ----
    {
      float av[8] = {ga0.x, ga0.y, ga0.z, ga0.w, ga1.x, ga1.y, ga1.z, ga1.w};
      float bv[8] = {gb0.x, gb0.y, gb0.z, gb0.w, gb1.x, gb1.y, gb1.z, gb1.w};
#pragma unroll
      for (int i = 0; i < 8; ++i)   // bank = (36*(vcg+i) + tid&31) & 31 -> all 32 banks
        *(unsigned*)&Vb[(vcg + i) * VSTR + vnr] = pk2(av[i], bv[i]);
    }

    // ---- issue next tile's loads (consumed at top of next iter / next V-stage) ----
    if (tile + 1 < NT) {
      const float* kn = kp + (size_t)(tile + 1) * BN * DH;
      const float* vn = vp + (size_t)(tile + 1) * BN * DH;
#pragma unroll
      for (int it = 0; it < 4; ++it)
        gk[it] = *(const float4*)(kn + (size_t)(krt + it * 16) * DH + kc);
      ga0 = *(const float4*)(vn + (size_t)vnr * DH + vcg);
      ga1 = *(const float4*)(vn + (size_t)vnr * DH + vcg + 4);
      gb0 = *(const float4*)(vn + (size_t)(vnr + 1) * DH + vcg);
      gb1 = *(const float4*)(vn + (size_t)(vnr + 1) * DH + vcg + 4);
    }

    // ---- S^T = K_tile · Q^T ----
    floatx16 st[2];
#pragma unroll
    for (int t = 0; t < 2; ++t)
#pragma unroll
      for (int r = 0; r < 16; ++r) st[t][r] = 0.f;
    __builtin_amdgcn_s_setprio(1);
#pragma unroll
    for (int kt = 0; kt < 4; ++kt) {
#pragma unroll
      for (int t = 0; t < 2; ++t) {
        half8 kf = *(const half8*)&Kb[(t * 32 + l31) * KSTR + kt * 16 + b8];
        st[t] = __builtin_amdgcn_mfma_f32_32x32x16_f16(kf, qf[kt], st[t], 0, 0, 0);
      }
    }
    __builtin_amdgcn_s_setprio(0);

    // ---- online softmax (lane owns q-row l31); ternary chains -> v_max3 ----
    float r0, r1, r2, r3;
    {
      float a[16];
#pragma unroll
      for (int r = 0; r < 16; ++r) a[r] = fmaxf(st[0][r], st[1][r]);
      r0 = fmaxf(fmaxf(a[0],  a[1]),  fmaxf(a[2],  a[3]));
      r1 = fmaxf(fmaxf(a[4],  a[5]),  fmaxf(a[6],  a[7]));
      r2 = fmaxf(fmaxf(a[8],  a[9]),  fmaxf(a[10], a[11]));
      r3 = fmaxf(fmaxf(a[12], a[13]), fmaxf(a[14], a[15]));
    }
    float mx = fmaxf(fmaxf(r0, r1), fmaxf(r2, r3));
    mx = fmaxf(mx, __shfl_xor(mx, 32, 64));
    float m_new = fmaxf(m_run, mx);
    float alpha = EXP2F(m_run - m_new);
    m_run = m_new;
#pragma unroll
    for (int t = 0; t < 2; ++t)
#pragma unroll
      for (int r = 0; r < 16; ++r)
        st[t][r] = EXP2F(st[t][r] - m_new);
    float sm[16];
#pragma unroll
    for (int r = 0; r < 16; ++r) sm[r] = st[0][r] + st[1][r];
#pragma unroll
    for (int s = 8; s >= 1; s >>= 1)
#pragma unroll
      for (int r = 0; r < 8; ++r)
        if (r < s) sm[r] += sm[r + s];
    float sum = sm[0] + __shfl_xor(sm[0], 32, 64);
    l_run = alpha * l_run + sum;

    if (__any(alpha != 1.0f)) {      // skip rescale once max has stabilized
#pragma unroll
      for (int r = 0; r < 16; ++r) {
        int row = (r & 3) + 8 * (r >> 2) + 4 * hb;
        float ar = __shfl(alpha, row, 64);
        accO[0][r] *= ar;
        accO[1][r] *= ar;
      }
    }

    WGBAR();                         // B2: V^T visible; QK reads of Kb drained

    // ---- P·V: C-layout -> A-layout via permlane32_swap (or shfl fallback) ----
    __builtin_amdgcn_s_setprio(1);
#pragma unroll
    for (int t = 0; t < 2; ++t) {
      unsigned P01 = pk2(st[t][0],  st[t][1]);
      unsigned P23 = pk2(st[t][2],  st[t][3]);
      unsigned P45 = pk2(st[t][4],  st[t][5]);
      unsigned P67 = pk2(st[t][6],  st[t][7]);
      unsigned P89 = pk2(st[t][8],  st[t][9]);
      unsigned PAB = pk2(st[t][10], st[t][11]);
      unsigned PCD = pk2(st[t][12], st[t][13]);
      unsigned PEF = pk2(st[t][14], st[t][15]);
      F8U fe, fo;
#if HAVE_PL32
      pl32(P01, P45); fe.u[0] = P01; fe.u[2] = P45;
      pl32(P23, P67); fe.u[1] = P23; fe.u[3] = P67;
      pl32(P89, PCD); fo.u[0] = P89; fo.u[2] = PCD;
      pl32(PAB, PEF); fo.u[1] = PAB; fo.u[3] = PEF;
#else
      unsigned x01 = __shfl_xor(P01, 32, 64), x23 = __shfl_xor(P23, 32, 64);
      unsigned x45 = __shfl_xor(P45, 32, 64), x67 = __shfl_xor(P67, 32, 64);
      unsigned x89 = __shfl_xor(P89, 32, 64), xAB = __shfl_xor(PAB, 32, 64);
      unsigned xCD = __shfl_xor(PCD, 32, 64), xEF = __shfl_xor(PEF, 32, 64);
      fe.u = uint4v{hb ? x45 : P01, hb ? x67 : P23, hb ? P45 : x01, hb ? P67 : x23};
      fo.u = uint4v{hb ? xCD : P89, hb ? xEF : PAB, hb ? PCD : x89, hb ? PEF : xAB};
#endif
#pragma unroll
      for (int ds = 0; ds < 2; ++ds) {
        half8 vf0 = *(const half8*)&Vb[(ds * 32 + l31) * VSTR + (2 * t) * 16 + b8];
        accO[ds] = __builtin_amdgcn_mfma_f32_32x32x16_f16(fe.h, vf0, accO[ds], 0, 0, 0);
        half8 vf1 = *(const half8*)&Vb[(ds * 32 + l31) * VSTR + (2 * t + 1) * 16 + b8];
        accO[ds] = __builtin_amdgcn_mfma_f32_32x32x16_f16(fo.h, vf1, accO[ds], 0, 0, 0);
      }
    }
    __builtin_amdgcn_s_setprio(0);
    buf ^= 1;
  }

  const int rowbase = batch * SQL + qb * BM + wv * 32;
  if (NSPLIT == 1) {
    float linv = 1.0f / l_run;
    float* op = out + (size_t)rowbase * DH;
#pragma unroll
    for (int r = 0; r < 16; ++r) {
      int row = (r & 3) + 8 * (r >> 2) + 4 * hb;
      float lr = __shfl(linv, row, 64);
      op[(size_t)row * DH + l31]      = accO[0][r] * lr;
      op[(size_t)row * DH + 32 + l31] = accO[1][r] * lr;
    }
  } else {
    // unnormalized partials + (m,l) per q-row
    float* po = pO + ((size_t)split * NBATCH * SQL + rowbase) * DH;
#pragma unroll
    for (int r = 0; r < 16; ++r) {
      int row = (r & 3) + 8 * (r >> 2) + 4 * hb;
      po[(size_t)row * DH + l31]      = accO[0][r];
      po[(size_t)row * DH + 32 + l31] = accO[1][r];
    }
    if (hb == 0) {
      pM[(size_t)split * NBATCH * SQL + rowbase + l31] = m_run;
      pL[(size_t)split * NBATCH * SQL + rowbase + l31] = l_run;
    }
  }
}

__global__ __launch_bounds__(256)
void merge4(const float* __restrict__ pO, const float* __restrict__ pM,
            const float* __restrict__ pL, float* __restrict__ out)
{
  const int i4   = blockIdx.x * 256 + threadIdx.x;    // float4 index
  const int rowg = i4 >> 4;                           // (i4*4)>>6
  const size_t PLANE4 = (size_t)NBATCH * SQL * DH / 4;  // 524288
  const int    RPL    = NBATCH * SQL;                   // 32768
  float m0 = pM[rowg], m1 = pM[RPL + rowg], m2 = pM[2 * RPL + rowg], m3 = pM[3 * RPL + rowg];
  float mx = fmaxf(fmaxf(m0, m1), fmaxf(m2, m3));
  float w0 = EXP2F(m0 - mx), w1 = EXP2F(m1 - mx), w2 = EXP2F(m2 - mx), w3 = EXP2F(m3 - mx);
  float l = w0 * pL[rowg] + w1 * pL[RPL + rowg] + w2 * pL[2 * RPL + rowg] + w3 * pL[3 * RPL + rowg];
  float li = 1.0f / l;
  const floatx4* p0 = (const floatx4*)pO;
  floatx4 o0 = p0[i4], o1 = p0[PLANE4 + i4], o2 = p0[2 * PLANE4 + i4], o3 = p0[3 * PLANE4 + i4];
  floatx4 o;
#pragma unroll
  for (int j = 0; j < 4; ++j)
    o[j] = (w0 * o0[j] + w1 * o1[j] + w2 * o2[j] + w3 * o3[j]) * li;
  ((floatx4*)out)[i4] = o;
}

extern "C" void kernel_launch(void* const* d_in, const int* in_sizes, int n_in,
                              void* d_out, int out_size, void* d_ws, size_t ws_size,
                              hipStream_t stream) {
  (void)in_sizes; (void)n_in; (void)out_size;
  const float* q = (const float*)d_in[0];
  const float* k = (const float*)d_in[1];
  const float* v = (const float*)d_in[2];
  float* out = (float*)d_out;

  const size_t PLANE = (size_t)NBATCH * SQL * DH;              // floats per split plane
  const size_t RPL   = (size_t)NBATCH * SQL;                   // rows per split
  const size_t need  = (4 * PLANE + 8 * RPL) * sizeof(float);  // 34.6 MB

  if (ws_size >= need) {
    float* pO = (float*)d_ws;
    float* pM = pO + 4 * PLANE;
    float* pL = pM + 4 * RPL;
    ring_attn<4><<<dim3(1024), dim3(256), 0, stream>>>(q, k, v, nullptr, pO, pM, pL);
    merge4<<<dim3((NBATCH * SQL * DH) / 1024), dim3(256), 0, stream>>>(pO, pM, pL, out);
  } else {
    ring_attn<1><<<dim3(256), dim3(256), 0, stream>>>(q, k, v, out, nullptr, nullptr, nullptr);
  }
}

// Round 4
// 271.702 us; speedup vs baseline: 1.1805x; 1.1805x over previous
//
#include <hip/hip_runtime.h>

// RingAttention: out = softmax(Q K^T) V (no scale), B=32 SQ=1024 SKV=8192 D=64, fp32 I/O.
// R10: full residency WITHOUT spills. R9 post-mortem: (256,4) forced unified reg budget
// 128 < demand ~140 (76 arch + 64 acc) -> ~12 regs spilled (WRITE_SIZE 33->56 MB),
// MfmaUtil 21->13. Fix: 512-thread blocks (8 waves, BM=256), grid = 32*4*4 = 512 =
// exactly 2 blocks/CU -> no scheduling tail; staging split over 2x threads halves
// per-thread prefetch regs (32->16) so unified demand ~124 fits the (512,4) budget 128.
// Guard counter: WRITE_SIZE must be ~33792 KB (no scratch).
// Carried from R8/R9: lgkmcnt-only raw barriers (no vmcnt drain), 2-barrier tile with
// V-stage/prefetch overlapped under QK+softmax, ternary max3 reduce, setprio on MFMA.
// Carried from R6: NSPLIT=4 split-K, register prefetch, single-fp16 Q, permlane32_swap
// P exchange, conflict-free V^T staging, dbuf LDS, fp16 MFMA 32x32x16 S^T formulation.

#define NBATCH 32
#define SQL 1024
#define SKVL 8192
#define DH 64
#define BM 256                 // q rows per block (8 waves x 32)
#define BN 64                  // kv rows per tile
#define KSTR 72                // K lds row stride in halfs
#define VSTR 72                // V^T lds row stride in halfs (36 dwords: b128 reads phase-optimal)

typedef _Float16 half8 __attribute__((ext_vector_type(8)));
typedef __fp16 fp16x2 __attribute__((ext_vector_type(2)));
typedef float floatx16 __attribute__((ext_vector_type(16)));
typedef float floatx4 __attribute__((ext_vector_type(4)));
typedef unsigned int uint4v __attribute__((ext_vector_type(4)));
typedef unsigned int uint2v __attribute__((ext_vector_type(2)));

union F8U { uint4v u; half8 h; };

#if __has_builtin(__builtin_amdgcn_exp2f)
#define EXP2F(x) __builtin_amdgcn_exp2f(x)
#else
#define EXP2F(x) exp2f(x)
#endif

// __syncthreads minus the vmcnt drain: wait own LDS ops, barrier, fence reordering.
#define WGBAR() do {                                        \
    asm volatile("s_waitcnt lgkmcnt(0)" ::: "memory");      \
    __builtin_amdgcn_s_barrier();                           \
    asm volatile("" ::: "memory");                          \
  } while (0)

static __device__ __forceinline__ unsigned pk2(float a, float b) {
#if __has_builtin(__builtin_amdgcn_cvt_pkrtz)
  fp16x2 h = __builtin_amdgcn_cvt_pkrtz(a, b);
  return __builtin_bit_cast(unsigned, h);
#else
  union { _Float16 h[2]; unsigned u; } r;
  r.h[0] = (_Float16)a; r.h[1] = (_Float16)b; return r.u;
#endif
}

#if __has_builtin(__builtin_amdgcn_permlane32_swap)
#define HAVE_PL32 1
// a' = [a.lo | b.lo], b' = [a.hi | b.hi]  (one VALU instr, both results)
static __device__ __forceinline__ void pl32(unsigned& a, unsigned& b) {
  uint2v r = __builtin_amdgcn_permlane32_swap(a, b, false, false);
  a = r[0]; b = r[1];
}
#else
#define HAVE_PL32 0
#endif

template<int NSPLIT>
__global__ __launch_bounds__(512, 4)
void ring_attn(const float* __restrict__ q, const float* __restrict__ k,
               const float* __restrict__ v, float* __restrict__ out,
               float* __restrict__ pO, float* __restrict__ pM, float* __restrict__ pL)
{
  constexpr int NT = SKVL / NSPLIT / BN;   // tiles per block
  __shared__ _Float16 Kl[2][BN * KSTR];
  __shared__ _Float16 Vt[2][DH * VSTR];

  const int tid  = threadIdx.x;
  const int lane = tid & 63;
  const int wv   = tid >> 6;       // 0..7
  const int l31  = lane & 31;
  const int hb   = lane >> 5;
  const int b8   = hb * 8;

  int split, batch, qb;
  if (NSPLIT == 4) {                 // bi = qb*128 + batch*4 + split, grid 512
    split = blockIdx.x & 3;          // qb-sharers of a K/V slice co-scheduled
    batch = (blockIdx.x >> 2) & 31;
    qb    = blockIdx.x >> 7;         // 0..3
  } else {
    split = 0;
    batch = blockIdx.x & 31;
    qb    = blockIdx.x >> 5;         // 0..3, grid 128
  }

  const float* kp = k + ((size_t)batch * SKVL + (size_t)split * (SKVL / NSPLIT)) * DH;
  const float* vp = v + ((size_t)batch * SKVL + (size_t)split * (SKVL / NSPLIT)) * DH;

  // ---- Q: scale by log2(e), round to fp16 (B-operand frags: n=q=l31, k=d) ----
  const float* qp = q + ((size_t)batch * SQL + qb * BM + wv * 32 + l31) * DH;
  half8 qf[4];
#pragma unroll
  for (int kt = 0; kt < 4; ++kt) {
    float4 a = *(const float4*)(qp + kt * 16 + b8);
    float4 c = *(const float4*)(qp + kt * 16 + b8 + 4);
    float xs[8] = {a.x, a.y, a.z, a.w, c.x, c.y, c.z, c.w};
#pragma unroll
    for (int j = 0; j < 8; ++j)
      qf[kt][j] = (_Float16)(xs[j] * 1.44269504088896340736f);
  }

  // K staging (512 thr): thread -> rows krt + (khalf*2+it)*16, cols kc..kc+3 (fp32)
  const int t8    = tid & 255;
  const int khalf = tid >> 8;        // 0/1
  const int krt   = t8 >> 4;         // 0..15
  const int kc    = (t8 & 15) * 4;
  // V staging (n-major, conflict-free): thread -> rows vnr,vnr+1, cols vcg4..vcg4+3
  const int vnr  = 2 * (tid & 31);
  const int vcg4 = 4 * (tid >> 5);   // 0..60

  float4 gk[2], ga, gb;
  // prefetch tile 0
#pragma unroll
  for (int it = 0; it < 2; ++it)
    gk[it] = *(const float4*)(kp + (size_t)(krt + (khalf * 2 + it) * 16) * DH + kc);
  ga = *(const float4*)(vp + (size_t)vnr * DH + vcg4);
  gb = *(const float4*)(vp + (size_t)(vnr + 1) * DH + vcg4);

  floatx16 accO[2];
#pragma unroll
  for (int i = 0; i < 2; ++i)
#pragma unroll
    for (int r = 0; r < 16; ++r) accO[i][r] = 0.f;
  float m_run = -3.0e38f, l_run = 0.f;

  int buf = 0;
  for (int tile = 0; tile < NT; ++tile) {
    _Float16* Kb = Kl[buf];
    _Float16* Vb = Vt[buf];

    // ---- stage K regs -> LDS[buf] (vmcnt for gk auto-counted by compiler) ----
#pragma unroll
    for (int it = 0; it < 2; ++it) {
      uint2 w2 = make_uint2(pk2(gk[it].x, gk[it].y), pk2(gk[it].z, gk[it].w));
      *(uint2*)&Kb[(krt + (khalf * 2 + it) * 16) * KSTR + kc] = w2;
    }
    WGBAR();                         // B1: K visible; V loads still in flight

    // ---- stage V regs -> LDS[buf] (overlaps QK below; compiler schedules) ----
    {
      float av[4] = {ga.x, ga.y, ga.z, ga.w};
      float bv[4] = {gb.x, gb.y, gb.z, gb.w};
#pragma unroll
      for (int i = 0; i < 4; ++i)
        *(unsigned*)&Vb[(vcg4 + i) * VSTR + vnr] = pk2(av[i], bv[i]);
    }

    // ---- issue next tile's loads (consumed at top of next iter / next V-stage) ----
    if (tile + 1 < NT) {
      const float* kn = kp + (size_t)(tile + 1) * BN * DH;
      const float* vn = vp + (size_t)(tile + 1) * BN * DH;
#pragma unroll
      for (int it = 0; it < 2; ++it)
        gk[it] = *(const float4*)(kn + (size_t)(krt + (khalf * 2 + it) * 16) * DH + kc);
      ga = *(const float4*)(vn + (size_t)vnr * DH + vcg4);
      gb = *(const float4*)(vn + (size_t)(vnr + 1) * DH + vcg4);
    }

    // ---- S^T = K_tile · Q^T ----
    floatx16 st[2];
#pragma unroll
    for (int t = 0; t < 2; ++t)
#pragma unroll
      for (int r = 0; r < 16; ++r) st[t][r] = 0.f;
    __builtin_amdgcn_s_setprio(1);
#pragma unroll
    for (int kt = 0; kt < 4; ++kt) {
#pragma unroll
      for (int t = 0; t < 2; ++t) {
        half8 kf = *(const half8*)&Kb[(t * 32 + l31) * KSTR + kt * 16 + b8];
        st[t] = __builtin_amdgcn_mfma_f32_32x32x16_f16(kf, qf[kt], st[t], 0, 0, 0);
      }
    }
    __builtin_amdgcn_s_setprio(0);

    // ---- online softmax (lane owns q-row l31); ternary chains -> v_max3 ----
    float r0, r1, r2, r3;
    {
      float a[16];
#pragma unroll
      for (int r = 0; r < 16; ++r) a[r] = fmaxf(st[0][r], st[1][r]);
      r0 = fmaxf(fmaxf(a[0],  a[1]),  fmaxf(a[2],  a[3]));
      r1 = fmaxf(fmaxf(a[4],  a[5]),  fmaxf(a[6],  a[7]));
      r2 = fmaxf(fmaxf(a[8],  a[9]),  fmaxf(a[10], a[11]));
      r3 = fmaxf(fmaxf(a[12], a[13]), fmaxf(a[14], a[15]));
    }
    float mx = fmaxf(fmaxf(r0, r1), fmaxf(r2, r3));
    mx = fmaxf(mx, __shfl_xor(mx, 32, 64));
    float m_new = fmaxf(m_run, mx);
    float alpha = EXP2F(m_run - m_new);
    m_run = m_new;
#pragma unroll
    for (int t = 0; t < 2; ++t)
#pragma unroll
      for (int r = 0; r < 16; ++r)
        st[t][r] = EXP2F(st[t][r] - m_new);
    float sm[16];
#pragma unroll
    for (int r = 0; r < 16; ++r) sm[r] = st[0][r] + st[1][r];
#pragma unroll
    for (int s = 8; s >= 1; s >>= 1)
#pragma unroll
      for (int r = 0; r < 8; ++r)
        if (r < s) sm[r] += sm[r + s];
    float sum = sm[0] + __shfl_xor(sm[0], 32, 64);
    l_run = alpha * l_run + sum;

    if (__any(alpha != 1.0f)) {      // skip rescale once max has stabilized
#pragma unroll
      for (int r = 0; r < 16; ++r) {
        int row = (r & 3) + 8 * (r >> 2) + 4 * hb;
        float ar = __shfl(alpha, row, 64);
        accO[0][r] *= ar;
        accO[1][r] *= ar;
      }
    }

    WGBAR();                         // B2: V^T visible; QK reads of Kb drained

    // ---- P·V: C-layout -> A-layout via permlane32_swap (or shfl fallback) ----
    __builtin_amdgcn_s_setprio(1);
#pragma unroll
    for (int t = 0; t < 2; ++t) {
      unsigned P01 = pk2(st[t][0],  st[t][1]);
      unsigned P23 = pk2(st[t][2],  st[t][3]);
      unsigned P45 = pk2(st[t][4],  st[t][5]);
      unsigned P67 = pk2(st[t][6],  st[t][7]);
      unsigned P89 = pk2(st[t][8],  st[t][9]);
      unsigned PAB = pk2(st[t][10], st[t][11]);
      unsigned PCD = pk2(st[t][12], st[t][13]);
      unsigned PEF = pk2(st[t][14], st[t][15]);
      F8U fe, fo;
#if HAVE_PL32
      pl32(P01, P45); fe.u[0] = P01; fe.u[2] = P45;
      pl32(P23, P67); fe.u[1] = P23; fe.u[3] = P67;
      pl32(P89, PCD); fo.u[0] = P89; fo.u[2] = PCD;
      pl32(PAB, PEF); fo.u[1] = PAB; fo.u[3] = PEF;
#else
      unsigned x01 = __shfl_xor(P01, 32, 64), x23 = __shfl_xor(P23, 32, 64);
      unsigned x45 = __shfl_xor(P45, 32, 64), x67 = __shfl_xor(P67, 32, 64);
      unsigned x89 = __shfl_xor(P89, 32, 64), xAB = __shfl_xor(PAB, 32, 64);
      unsigned xCD = __shfl_xor(PCD, 32, 64), xEF = __shfl_xor(PEF, 32, 64);
      fe.u = uint4v{hb ? x45 : P01, hb ? x67 : P23, hb ? P45 : x01, hb ? P67 : x23};
      fo.u = uint4v{hb ? xCD : P89, hb ? xEF : PAB, hb ? PCD : x89, hb ? PEF : xAB};
#endif
#pragma unroll
      for (int ds = 0; ds < 2; ++ds) {
        half8 vf0 = *(const half8*)&Vb[(ds * 32 + l31) * VSTR + (2 * t) * 16 + b8];
        accO[ds] = __builtin_amdgcn_mfma_f32_32x32x16_f16(fe.h, vf0, accO[ds], 0, 0, 0);
        half8 vf1 = *(const half8*)&Vb[(ds * 32 + l31) * VSTR + (2 * t + 1) * 16 + b8];
        accO[ds] = __builtin_amdgcn_mfma_f32_32x32x16_f16(fo.h, vf1, accO[ds], 0, 0, 0);
      }
    }
    __builtin_amdgcn_s_setprio(0);
    buf ^= 1;
  }

  const int rowbase = batch * SQL + qb * BM + wv * 32;
  if (NSPLIT == 1) {
    float linv = 1.0f / l_run;
    float* op = out + (size_t)rowbase * DH;
#pragma unroll
    for (int r = 0; r < 16; ++r) {
      int row = (r & 3) + 8 * (r >> 2) + 4 * hb;
      float lr = __shfl(linv, row, 64);
      op[(size_t)row * DH + l31]      = accO[0][r] * lr;
      op[(size_t)row * DH + 32 + l31] = accO[1][r] * lr;
    }
  } else {
    // unnormalized partials + (m,l) per q-row
    float* po = pO + ((size_t)split * NBATCH * SQL + rowbase) * DH;
#pragma unroll
    for (int r = 0; r < 16; ++r) {
      int row = (r & 3) + 8 * (r >> 2) + 4 * hb;
      po[(size_t)row * DH + l31]      = accO[0][r];
      po[(size_t)row * DH + 32 + l31] = accO[1][r];
    }
    if (hb == 0) {
      pM[(size_t)split * NBATCH * SQL + rowbase + l31] = m_run;
      pL[(size_t)split * NBATCH * SQL + rowbase + l31] = l_run;
    }
  }
}

__global__ __launch_bounds__(256)
void merge4(const float* __restrict__ pO, const float* __restrict__ pM,
            const float* __restrict__ pL, float* __restrict__ out)
{
  const int i4   = blockIdx.x * 256 + threadIdx.x;    // float4 index
  const int rowg = i4 >> 4;                           // (i4*4)>>6
  const size_t PLANE4 = (size_t)NBATCH * SQL * DH / 4;  // 524288
  const int    RPL    = NBATCH * SQL;                   // 32768
  float m0 = pM[rowg], m1 = pM[RPL + rowg], m2 = pM[2 * RPL + rowg], m3 = pM[3 * RPL + rowg];
  float mx = fmaxf(fmaxf(m0, m1), fmaxf(m2, m3));
  float w0 = EXP2F(m0 - mx), w1 = EXP2F(m1 - mx), w2 = EXP2F(m2 - mx), w3 = EXP2F(m3 - mx);
  float l = w0 * pL[rowg] + w1 * pL[RPL + rowg] + w2 * pL[2 * RPL + rowg] + w3 * pL[3 * RPL + rowg];
  float li = 1.0f / l;
  const floatx4* p0 = (const floatx4*)pO;
  floatx4 o0 = p0[i4], o1 = p0[PLANE4 + i4], o2 = p0[2 * PLANE4 + i4], o3 = p0[3 * PLANE4 + i4];
  floatx4 o;
#pragma unroll
  for (int j = 0; j < 4; ++j)
    o[j] = (w0 * o0[j] + w1 * o1[j] + w2 * o2[j] + w3 * o3[j]) * li;
  ((floatx4*)out)[i4] = o;
}

extern "C" void kernel_launch(void* const* d_in, const int* in_sizes, int n_in,
                              void* d_out, int out_size, void* d_ws, size_t ws_size,
                              hipStream_t stream) {
  (void)in_sizes; (void)n_in; (void)out_size;
  const float* q = (const float*)d_in[0];
  const float* k = (const float*)d_in[1];
  const float* v = (const float*)d_in[2];
  float* out = (float*)d_out;

  const size_t PLANE = (size_t)NBATCH * SQL * DH;              // floats per split plane
  const size_t RPL   = (size_t)NBATCH * SQL;                   // rows per split
  const size_t need  = (4 * PLANE + 8 * RPL) * sizeof(float);  // 34.6 MB

  if (ws_size >= need) {
    float* pO = (float*)d_ws;
    float* pM = pO + 4 * PLANE;
    float* pL = pM + 4 * RPL;
    ring_attn<4><<<dim3(512), dim3(512), 0, stream>>>(q, k, v, nullptr, pO, pM, pL);
    merge4<<<dim3((NBATCH * SQL * DH) / 1024), dim3(256), 0, stream>>>(pO, pM, pL, out);
  } else {
    ring_attn<1><<<dim3(128), dim3(512), 0, stream>>>(q, k, v, out, nullptr, nullptr, nullptr);
  }
}

// Round 5
// 236.010 us; speedup vs baseline: 1.3591x; 1.1512x over previous
//
#include <hip/hip_runtime.h>

// RingAttention: out = softmax(Q K^T) V (no scale), B=32 SQ=1024 SKV=8192 D=64, fp32 I/O.
// R11: zero-tail grid at R8's no-spill register point. R9/R10 proved 4 waves/SIMD is
// unreachable (unified demand ~140 > 128 budget -> spills, WRITE_SIZE ballooned).
// R8's real problem: grid 1024 @ 3 blocks/CU -> 768 resident + 256-block serial tail
// (~+33% wall) whose K/V re-fetches caused the 2.3x FETCH overread.
//  - NSPLIT=3: grid = 8 qb x 32 batch x 3 split = 768 = exactly 3 blocks/CU. Uneven
//    tile ranges (42/43/43) via t=(s*128)/3 — online-softmax partials merge fine.
//  - K/V-slice sharers are 96 apart in bid; 96%8==0 -> same XCD; slice (2.8MB) fits
//    the XCD L2 (4MB) -> FETCH should approach unique bytes (R10 evidence: 132MB).
//  - merge3 combines 3 partial planes.
// Guard counters: WRITE_SIZE ~26MB (no spill), VGPR ~76.
// Carried from R8: (256,3), lgkmcnt-only raw barriers (no vmcnt drain), 2-barrier tile
// with V-stage/prefetch under QK+softmax, ternary max3 reduce, setprio on MFMA,
// register prefetch, single-fp16 Q, permlane32_swap P exchange, conflict-free V^T
// staging, dbuf LDS, fp16 MFMA 32x32x16 S^T formulation.

#define NBATCH 32
#define SQL 1024
#define SKVL 8192
#define DH 64
#define BM 128                 // q rows per block (4 waves x 32)
#define BN 64                  // kv rows per tile
#define KSTR 72                // K lds row stride in halfs
#define VSTR 72                // V^T lds row stride in halfs (36 dwords: b128 reads phase-optimal)
#define NSPL 3                 // splits per (batch,qb): grid 768 = 3 blocks/CU exactly

typedef _Float16 half8 __attribute__((ext_vector_type(8)));
typedef __fp16 fp16x2 __attribute__((ext_vector_type(2)));
typedef float floatx16 __attribute__((ext_vector_type(16)));
typedef float floatx4 __attribute__((ext_vector_type(4)));
typedef unsigned int uint4v __attribute__((ext_vector_type(4)));
typedef unsigned int uint2v __attribute__((ext_vector_type(2)));

union F8U { uint4v u; half8 h; };

#if __has_builtin(__builtin_amdgcn_exp2f)
#define EXP2F(x) __builtin_amdgcn_exp2f(x)
#else
#define EXP2F(x) exp2f(x)
#endif

// __syncthreads minus the vmcnt drain: wait own LDS ops, barrier, fence reordering.
#define WGBAR() do {                                        \
    asm volatile("s_waitcnt lgkmcnt(0)" ::: "memory");      \
    __builtin_amdgcn_s_barrier();                           \
    asm volatile("" ::: "memory");                          \
  } while (0)

static __device__ __forceinline__ unsigned pk2(float a, float b) {
#if __has_builtin(__builtin_amdgcn_cvt_pkrtz)
  fp16x2 h = __builtin_amdgcn_cvt_pkrtz(a, b);
  return __builtin_bit_cast(unsigned, h);
#else
  union { _Float16 h[2]; unsigned u; } r;
  r.h[0] = (_Float16)a; r.h[1] = (_Float16)b; return r.u;
#endif
}

#if __has_builtin(__builtin_amdgcn_permlane32_swap)
#define HAVE_PL32 1
// a' = [a.lo | b.lo], b' = [a.hi | b.hi]  (one VALU instr, both results)
static __device__ __forceinline__ void pl32(unsigned& a, unsigned& b) {
  uint2v r = __builtin_amdgcn_permlane32_swap(a, b, false, false);
  a = r[0]; b = r[1];
}
#else
#define HAVE_PL32 0
#endif

template<int NSPLIT>
__global__ __launch_bounds__(256, 3)
void ring_attn(const float* __restrict__ q, const float* __restrict__ k,
               const float* __restrict__ v, float* __restrict__ out,
               float* __restrict__ pO, float* __restrict__ pM, float* __restrict__ pL)
{
  constexpr int TT = SKVL / BN;            // 128 kv tiles total
  __shared__ _Float16 Kl[2][BN * KSTR];
  __shared__ _Float16 Vt[2][DH * VSTR];

  const int tid  = threadIdx.x;
  const int lane = tid & 63;
  const int wv   = tid >> 6;
  const int l31  = lane & 31;
  const int hb   = lane >> 5;
  const int b8   = hb * 8;

  int split, batch, qb;
  if (NSPLIT == 3) {                 // bi = qb*96 + batch*3 + split, grid 768
    split = blockIdx.x % 3;          // sharers of a K/V slice: bid stride 96 == same XCD
    batch = (blockIdx.x / 3) & 31;
    qb    = blockIdx.x / 96;         // 0..7
  } else {
    split = 0;
    batch = blockIdx.x & 31;
    qb    = blockIdx.x >> 5;
  }
  const int t0 = (split * TT) / NSPLIT;        // 0,42,85 for NSPLIT=3
  const int t1 = ((split + 1) * TT) / NSPLIT;  // 42,85,128

  const float* kp = k + (size_t)batch * SKVL * DH;
  const float* vp = v + (size_t)batch * SKVL * DH;

  // ---- Q: scale by log2(e), round to fp16 (B-operand frags: n=q=l31, k=d) ----
  const float* qp = q + ((size_t)batch * SQL + qb * BM + wv * 32 + l31) * DH;
  half8 qf[4];
#pragma unroll
  for (int kt = 0; kt < 4; ++kt) {
    float4 a = *(const float4*)(qp + kt * 16 + b8);
    float4 c = *(const float4*)(qp + kt * 16 + b8 + 4);
    float xs[8] = {a.x, a.y, a.z, a.w, c.x, c.y, c.z, c.w};
#pragma unroll
    for (int j = 0; j < 8; ++j)
      qf[kt][j] = (_Float16)(xs[j] * 1.44269504088896340736f);
  }

  // K staging: thread -> row krt(+16*it), cols kc..kc+3 (fp32)
  const int krt = tid >> 4;
  const int kc  = (tid & 15) * 4;
  // V staging (n-major, conflict-free): thread -> rows vnr,vnr+1, cols vcg..vcg+7
  const int vnr = 2 * (tid & 31);
  const int vcg = 8 * (tid >> 5);

  float4 gk[4], ga0, ga1, gb0, gb1;
  // prefetch tile t0
  {
    const float* kt_ = kp + (size_t)t0 * BN * DH;
    const float* vt_ = vp + (size_t)t0 * BN * DH;
#pragma unroll
    for (int it = 0; it < 4; ++it)
      gk[it] = *(const float4*)(kt_ + (size_t)(krt + it * 16) * DH + kc);
    ga0 = *(const float4*)(vt_ + (size_t)vnr * DH + vcg);
    ga1 = *(const float4*)(vt_ + (size_t)vnr * DH + vcg + 4);
    gb0 = *(const float4*)(vt_ + (size_t)(vnr + 1) * DH + vcg);
    gb1 = *(const float4*)(vt_ + (size_t)(vnr + 1) * DH + vcg + 4);
  }

  floatx16 accO[2];
#pragma unroll
  for (int i = 0; i < 2; ++i)
#pragma unroll
    for (int r = 0; r < 16; ++r) accO[i][r] = 0.f;
  float m_run = -3.0e38f, l_run = 0.f;

  int buf = 0;
  for (int tile = t0; tile < t1; ++tile) {
    _Float16* Kb = Kl[buf];
    _Float16* Vb = Vt[buf];

    // ---- stage K regs -> LDS[buf] (vmcnt for gk auto-counted by compiler) ----
#pragma unroll
    for (int it = 0; it < 4; ++it) {
      uint2 w2 = make_uint2(pk2(gk[it].x, gk[it].y), pk2(gk[it].z, gk[it].w));
      *(uint2*)&Kb[(krt + it * 16) * KSTR + kc] = w2;
    }
    WGBAR();                         // B1: K visible; V loads still in flight

    // ---- stage V regs -> LDS[buf] (overlaps QK below; compiler schedules) ----
    {
      float av[8] = {ga0.x, ga0.y, ga0.z, ga0.w, ga1.x, ga1.y, ga1.z, ga1.w};
      float bv[8] = {gb0.x, gb0.y, gb0.z, gb0.w, gb1.x, gb1.y, gb1.z, gb1.w};
#pragma unroll
      for (int i = 0; i < 8; ++i)   // bank = (36*(vcg+i) + tid&31) & 31 -> all 32 banks
        *(unsigned*)&Vb[(vcg + i) * VSTR + vnr] = pk2(av[i], bv[i]);
    }

    // ---- issue next tile's loads (consumed at top of next iter / next V-stage) ----
    if (tile + 1 < t1) {
      const float* kn = kp + (size_t)(tile + 1) * BN * DH;
      const float* vn = vp + (size_t)(tile + 1) * BN * DH;
#pragma unroll
      for (int it = 0; it < 4; ++it)
        gk[it] = *(const float4*)(kn + (size_t)(krt + it * 16) * DH + kc);
      ga0 = *(const float4*)(vn + (size_t)vnr * DH + vcg);
      ga1 = *(const float4*)(vn + (size_t)vnr * DH + vcg + 4);
      gb0 = *(const float4*)(vn + (size_t)(vnr + 1) * DH + vcg);
      gb1 = *(const float4*)(vn + (size_t)(vnr + 1) * DH + vcg + 4);
    }

    // ---- S^T = K_tile · Q^T ----
    floatx16 st[2];
#pragma unroll
    for (int t = 0; t < 2; ++t)
#pragma unroll
      for (int r = 0; r < 16; ++r) st[t][r] = 0.f;
    __builtin_amdgcn_s_setprio(1);
#pragma unroll
    for (int kt = 0; kt < 4; ++kt) {
#pragma unroll
      for (int t = 0; t < 2; ++t) {
        half8 kf = *(const half8*)&Kb[(t * 32 + l31) * KSTR + kt * 16 + b8];
        st[t] = __builtin_amdgcn_mfma_f32_32x32x16_f16(kf, qf[kt], st[t], 0, 0, 0);
      }
    }
    __builtin_amdgcn_s_setprio(0);

    // ---- online softmax (lane owns q-row l31); ternary chains -> v_max3 ----
    float r0, r1, r2, r3;
    {
      float a[16];
#pragma unroll
      for (int r = 0; r < 16; ++r) a[r] = fmaxf(st[0][r], st[1][r]);
      r0 = fmaxf(fmaxf(a[0],  a[1]),  fmaxf(a[2],  a[3]));
      r1 = fmaxf(fmaxf(a[4],  a[5]),  fmaxf(a[6],  a[7]));
      r2 = fmaxf(fmaxf(a[8],  a[9]),  fmaxf(a[10], a[11]));
      r3 = fmaxf(fmaxf(a[12], a[13]), fmaxf(a[14], a[15]));
    }
    float mx = fmaxf(fmaxf(r0, r1), fmaxf(r2, r3));
    mx = fmaxf(mx, __shfl_xor(mx, 32, 64));
    float m_new = fmaxf(m_run, mx);
    float alpha = EXP2F(m_run - m_new);
    m_run = m_new;
#pragma unroll
    for (int t = 0; t < 2; ++t)
#pragma unroll
      for (int r = 0; r < 16; ++r)
        st[t][r] = EXP2F(st[t][r] - m_new);
    float sm[16];
#pragma unroll
    for (int r = 0; r < 16; ++r) sm[r] = st[0][r] + st[1][r];
#pragma unroll
    for (int s = 8; s >= 1; s >>= 1)
#pragma unroll
      for (int r = 0; r < 8; ++r)
        if (r < s) sm[r] += sm[r + s];
    float sum = sm[0] + __shfl_xor(sm[0], 32, 64);
    l_run = alpha * l_run + sum;

    if (__any(alpha != 1.0f)) {      // skip rescale once max has stabilized
#pragma unroll
      for (int r = 0; r < 16; ++r) {
        int row = (r & 3) + 8 * (r >> 2) + 4 * hb;
        float ar = __shfl(alpha, row, 64);
        accO[0][r] *= ar;
        accO[1][r] *= ar;
      }
    }

    WGBAR();                         // B2: V^T visible; QK reads of Kb drained

    // ---- P·V: C-layout -> A-layout via permlane32_swap (or shfl fallback) ----
    __builtin_amdgcn_s_setprio(1);
#pragma unroll
    for (int t = 0; t < 2; ++t) {
      unsigned P01 = pk2(st[t][0],  st[t][1]);
      unsigned P23 = pk2(st[t][2],  st[t][3]);
      unsigned P45 = pk2(st[t][4],  st[t][5]);
      unsigned P67 = pk2(st[t][6],  st[t][7]);
      unsigned P89 = pk2(st[t][8],  st[t][9]);
      unsigned PAB = pk2(st[t][10], st[t][11]);
      unsigned PCD = pk2(st[t][12], st[t][13]);
      unsigned PEF = pk2(st[t][14], st[t][15]);
      F8U fe, fo;
#if HAVE_PL32
      pl32(P01, P45); fe.u[0] = P01; fe.u[2] = P45;
      pl32(P23, P67); fe.u[1] = P23; fe.u[3] = P67;
      pl32(P89, PCD); fo.u[0] = P89; fo.u[2] = PCD;
      pl32(PAB, PEF); fo.u[1] = PAB; fo.u[3] = PEF;
#else
      unsigned x01 = __shfl_xor(P01, 32, 64), x23 = __shfl_xor(P23, 32, 64);
      unsigned x45 = __shfl_xor(P45, 32, 64), x67 = __shfl_xor(P67, 32, 64);
      unsigned x89 = __shfl_xor(P89, 32, 64), xAB = __shfl_xor(PAB, 32, 64);
      unsigned xCD = __shfl_xor(PCD, 32, 64), xEF = __shfl_xor(PEF, 32, 64);
      fe.u = uint4v{hb ? x45 : P01, hb ? x67 : P23, hb ? P45 : x01, hb ? P67 : x23};
      fo.u = uint4v{hb ? xCD : P89, hb ? xEF : PAB, hb ? PCD : x89, hb ? PEF : xAB};
#endif
#pragma unroll
      for (int ds = 0; ds < 2; ++ds) {
        half8 vf0 = *(const half8*)&Vb[(ds * 32 + l31) * VSTR + (2 * t) * 16 + b8];
        accO[ds] = __builtin_amdgcn_mfma_f32_32x32x16_f16(fe.h, vf0, accO[ds], 0, 0, 0);
        half8 vf1 = *(const half8*)&Vb[(ds * 32 + l31) * VSTR + (2 * t + 1) * 16 + b8];
        accO[ds] = __builtin_amdgcn_mfma_f32_32x32x16_f16(fo.h, vf1, accO[ds], 0, 0, 0);
      }
    }
    __builtin_amdgcn_s_setprio(0);
    buf ^= 1;
  }

  const int rowbase = batch * SQL + qb * BM + wv * 32;
  if (NSPLIT == 1) {
    float linv = 1.0f / l_run;
    float* op = out + (size_t)rowbase * DH;
#pragma unroll
    for (int r = 0; r < 16; ++r) {
      int row = (r & 3) + 8 * (r >> 2) + 4 * hb;
      float lr = __shfl(linv, row, 64);
      op[(size_t)row * DH + l31]      = accO[0][r] * lr;
      op[(size_t)row * DH + 32 + l31] = accO[1][r] * lr;
    }
  } else {
    // unnormalized partials + (m,l) per q-row
    float* po = pO + ((size_t)split * NBATCH * SQL + rowbase) * DH;
#pragma unroll
    for (int r = 0; r < 16; ++r) {
      int row = (r & 3) + 8 * (r >> 2) + 4 * hb;
      po[(size_t)row * DH + l31]      = accO[0][r];
      po[(size_t)row * DH + 32 + l31] = accO[1][r];
    }
    if (hb == 0) {
      pM[(size_t)split * NBATCH * SQL + rowbase + l31] = m_run;
      pL[(size_t)split * NBATCH * SQL + rowbase + l31] = l_run;
    }
  }
}

__global__ __launch_bounds__(256)
void merge3(const float* __restrict__ pO, const float* __restrict__ pM,
            const float* __restrict__ pL, float* __restrict__ out)
{
  const int i4   = blockIdx.x * 256 + threadIdx.x;    // float4 index
  const int rowg = i4 >> 4;                           // (i4*4)>>6
  const size_t PLANE4 = (size_t)NBATCH * SQL * DH / 4;  // 524288
  const int    RPL    = NBATCH * SQL;                   // 32768
  float m0 = pM[rowg], m1 = pM[RPL + rowg], m2 = pM[2 * RPL + rowg];
  float mx = fmaxf(fmaxf(m0, m1), m2);
  float w0 = EXP2F(m0 - mx), w1 = EXP2F(m1 - mx), w2 = EXP2F(m2 - mx);
  float l = w0 * pL[rowg] + w1 * pL[RPL + rowg] + w2 * pL[2 * RPL + rowg];
  float li = 1.0f / l;
  const floatx4* p0 = (const floatx4*)pO;
  floatx4 o0 = p0[i4], o1 = p0[PLANE4 + i4], o2 = p0[2 * PLANE4 + i4];
  floatx4 o;
#pragma unroll
  for (int j = 0; j < 4; ++j)
    o[j] = (w0 * o0[j] + w1 * o1[j] + w2 * o2[j]) * li;
  ((floatx4*)out)[i4] = o;
}

extern "C" void kernel_launch(void* const* d_in, const int* in_sizes, int n_in,
                              void* d_out, int out_size, void* d_ws, size_t ws_size,
                              hipStream_t stream) {
  (void)in_sizes; (void)n_in; (void)out_size;
  const float* q = (const float*)d_in[0];
  const float* k = (const float*)d_in[1];
  const float* v = (const float*)d_in[2];
  float* out = (float*)d_out;

  const size_t PLANE = (size_t)NBATCH * SQL * DH;              // floats per split plane
  const size_t RPL   = (size_t)NBATCH * SQL;                   // rows per split
  const size_t need  = (3 * PLANE + 6 * RPL) * sizeof(float);  // ~26 MB

  if (ws_size >= need) {
    float* pO = (float*)d_ws;
    float* pM = pO + 3 * PLANE;
    float* pL = pM + 3 * RPL;
    ring_attn<NSPL><<<dim3(768), dim3(256), 0, stream>>>(q, k, v, nullptr, pO, pM, pL);
    merge3<<<dim3((NBATCH * SQL * DH) / 1024), dim3(256), 0, stream>>>(pO, pM, pL, out);
  } else {
    ring_attn<1><<<dim3(256), dim3(256), 0, stream>>>(q, k, v, out, nullptr, nullptr, nullptr);
  }
}

// Round 6
// 231.989 us; speedup vs baseline: 1.3826x; 1.0173x over previous
//
#include <hip/hip_runtime.h>

// RingAttention: out = softmax(Q K^T) V (no scale), B=32 SQ=1024 SKV=8192 D=64, fp32 I/O.
// R12: structural VALU cut at R11's verified grid/residency point (768 blocks = 3/CU,
// no spill). R11 measured 135.6us, VALUBusy 50 / MfmaUtil 23 -> per-tile softmax
// bookkeeping VALU is the binding constraint. Three cuts:
//  1) st init = -m_run (fuses max-subtract into QK accumulate) + defer-max THR=8
//     (T13): common tiles skip subtract/alpha/rescale/m-update entirely. fp16 P<=256.
//  2) l via MFMA ones-trick: accL = mfma(P, ONES, accL) accumulates row sums in the
//     matrix pipe; kills the 31-add sum tree + shfl + l_run VALU per tile. Rescale of
//     accL reuses the rare-path row-alpha broadcast.
//  3) epilogue l read directly from accL (all lanes hold it; no shfl).
// Guard counters: WRITE_SIZE must stay 25344 KB (no spill); VGPR <= ~92.
// Carried from R11: NSPLIT=3 zero-tail grid, same-XCD K/V sharers, merge3.
// Carried from R8: (256,3), lgkmcnt-only raw barriers, 2-barrier tile with V-stage +
// prefetch under QK, ternary max3 reduce, setprio on MFMA, register prefetch,
// single-fp16 Q, permlane32_swap P exchange, conflict-free V^T staging, dbuf LDS,
// fp16 MFMA 32x32x16 S^T formulation.

#define NBATCH 32
#define SQL 1024
#define SKVL 8192
#define DH 64
#define BM 128                 // q rows per block (4 waves x 32)
#define BN 64                  // kv rows per tile
#define KSTR 72                // K lds row stride in halfs
#define VSTR 72                // V^T lds row stride in halfs
#define NSPL 3                 // splits per (batch,qb): grid 768 = 3 blocks/CU exactly
#define RESCALE_THR 8.0f       // defer-max threshold (fp16 P <= 2^8)

typedef _Float16 half8 __attribute__((ext_vector_type(8)));
typedef __fp16 fp16x2 __attribute__((ext_vector_type(2)));
typedef float floatx16 __attribute__((ext_vector_type(16)));
typedef float floatx4 __attribute__((ext_vector_type(4)));
typedef unsigned int uint4v __attribute__((ext_vector_type(4)));
typedef unsigned int uint2v __attribute__((ext_vector_type(2)));

union F8U { uint4v u; half8 h; };

#if __has_builtin(__builtin_amdgcn_exp2f)
#define EXP2F(x) __builtin_amdgcn_exp2f(x)
#else
#define EXP2F(x) exp2f(x)
#endif

// __syncthreads minus the vmcnt drain: wait own LDS ops, barrier, fence reordering.
#define WGBAR() do {                                        \
    asm volatile("s_waitcnt lgkmcnt(0)" ::: "memory");      \
    __builtin_amdgcn_s_barrier();                           \
    asm volatile("" ::: "memory");                          \
  } while (0)

static __device__ __forceinline__ unsigned pk2(float a, float b) {
#if __has_builtin(__builtin_amdgcn_cvt_pkrtz)
  fp16x2 h = __builtin_amdgcn_cvt_pkrtz(a, b);
  return __builtin_bit_cast(unsigned, h);
#else
  union { _Float16 h[2]; unsigned u; } r;
  r.h[0] = (_Float16)a; r.h[1] = (_Float16)b; return r.u;
#endif
}

#if __has_builtin(__builtin_amdgcn_permlane32_swap)
#define HAVE_PL32 1
static __device__ __forceinline__ void pl32(unsigned& a, unsigned& b) {
  uint2v r = __builtin_amdgcn_permlane32_swap(a, b, false, false);
  a = r[0]; b = r[1];
}
#else
#define HAVE_PL32 0
#endif

template<int NSPLIT>
__global__ __launch_bounds__(256, 3)
void ring_attn(const float* __restrict__ q, const float* __restrict__ k,
               const float* __restrict__ v, float* __restrict__ out,
               float* __restrict__ pO, float* __restrict__ pM, float* __restrict__ pL)
{
  constexpr int TT = SKVL / BN;            // 128 kv tiles total
  __shared__ _Float16 Kl[2][BN * KSTR];
  __shared__ _Float16 Vt[2][DH * VSTR];

  const int tid  = threadIdx.x;
  const int lane = tid & 63;
  const int wv   = tid >> 6;
  const int l31  = lane & 31;
  const int hb   = lane >> 5;
  const int b8   = hb * 8;

  int split, batch, qb;
  if (NSPLIT == 3) {                 // bi = qb*96 + batch*3 + split, grid 768
    split = blockIdx.x % 3;          // sharers of a K/V slice: bid stride 96 == same XCD
    batch = (blockIdx.x / 3) & 31;
    qb    = blockIdx.x / 96;         // 0..7
  } else {
    split = 0;
    batch = blockIdx.x & 31;
    qb    = blockIdx.x >> 5;
  }
  const int t0 = (split * TT) / NSPLIT;
  const int t1 = ((split + 1) * TT) / NSPLIT;

  const float* kp = k + (size_t)batch * SKVL * DH;
  const float* vp = v + (size_t)batch * SKVL * DH;

  // ---- Q: scale by log2(e), round to fp16 (B-operand frags: n=q=l31, k=d) ----
  const float* qp = q + ((size_t)batch * SQL + qb * BM + wv * 32 + l31) * DH;
  half8 qf[4];
#pragma unroll
  for (int kt = 0; kt < 4; ++kt) {
    float4 a = *(const float4*)(qp + kt * 16 + b8);
    float4 c = *(const float4*)(qp + kt * 16 + b8 + 4);
    float xs[8] = {a.x, a.y, a.z, a.w, c.x, c.y, c.z, c.w};
#pragma unroll
    for (int j = 0; j < 8; ++j)
      qf[kt][j] = (_Float16)(xs[j] * 1.44269504088896340736f);
  }

  // all-ones B operand for the row-sum (l) MFMA
  half8 ones;
#pragma unroll
  for (int j = 0; j < 8; ++j) ones[j] = (_Float16)1.0f;

  // K staging: thread -> row krt(+16*it), cols kc..kc+3 (fp32)
  const int krt = tid >> 4;
  const int kc  = (tid & 15) * 4;
  // V staging (n-major, conflict-free): thread -> rows vnr,vnr+1, cols vcg..vcg+7
  const int vnr = 2 * (tid & 31);
  const int vcg = 8 * (tid >> 5);

  float4 gk[4], ga0, ga1, gb0, gb1;
  {
    const float* kt_ = kp + (size_t)t0 * BN * DH;
    const float* vt_ = vp + (size_t)t0 * BN * DH;
#pragma unroll
    for (int it = 0; it < 4; ++it)
      gk[it] = *(const float4*)(kt_ + (size_t)(krt + it * 16) * DH + kc);
    ga0 = *(const float4*)(vt_ + (size_t)vnr * DH + vcg);
    ga1 = *(const float4*)(vt_ + (size_t)vnr * DH + vcg + 4);
    gb0 = *(const float4*)(vt_ + (size_t)(vnr + 1) * DH + vcg);
    gb1 = *(const float4*)(vt_ + (size_t)(vnr + 1) * DH + vcg + 4);
  }

  floatx16 accO[2], accL;
#pragma unroll
  for (int i = 0; i < 2; ++i)
#pragma unroll
    for (int r = 0; r < 16; ++r) accO[i][r] = 0.f;
#pragma unroll
  for (int r = 0; r < 16; ++r) accL[r] = 0.f;
  float m_run = 0.f;               // deferred running max (lane = q-row l31)

  int buf = 0;
  for (int tile = t0; tile < t1; ++tile) {
    _Float16* Kb = Kl[buf];
    _Float16* Vb = Vt[buf];

    // ---- stage K regs -> LDS[buf] ----
#pragma unroll
    for (int it = 0; it < 4; ++it) {
      uint2 w2 = make_uint2(pk2(gk[it].x, gk[it].y), pk2(gk[it].z, gk[it].w));
      *(uint2*)&Kb[(krt + it * 16) * KSTR + kc] = w2;
    }
    WGBAR();                         // B1: K visible; V loads still in flight

    // ---- stage V regs -> LDS[buf] (overlaps QK below) ----
    {
      float av[8] = {ga0.x, ga0.y, ga0.z, ga0.w, ga1.x, ga1.y, ga1.z, ga1.w};
      float bv[8] = {gb0.x, gb0.y, gb0.z, gb0.w, gb1.x, gb1.y, gb1.z, gb1.w};
#pragma unroll
      for (int i = 0; i < 8; ++i)
        *(unsigned*)&Vb[(vcg + i) * VSTR + vnr] = pk2(av[i], bv[i]);
    }

    // ---- issue next tile's loads ----
    if (tile + 1 < t1) {
      const float* kn = kp + (size_t)(tile + 1) * BN * DH;
      const float* vn = vp + (size_t)(tile + 1) * BN * DH;
#pragma unroll
      for (int it = 0; it < 4; ++it)
        gk[it] = *(const float4*)(kn + (size_t)(krt + it * 16) * DH + kc);
      ga0 = *(const float4*)(vn + (size_t)vnr * DH + vcg);
      ga1 = *(const float4*)(vn + (size_t)vnr * DH + vcg + 4);
      gb0 = *(const float4*)(vn + (size_t)(vnr + 1) * DH + vcg);
      gb1 = *(const float4*)(vn + (size_t)(vnr + 1) * DH + vcg + 4);
    }

    // ---- S' = K_tile · Q^T - m_run  (subtract fused via C-init) ----
    const float negm = -m_run;
    floatx16 st[2];
#pragma unroll
    for (int t = 0; t < 2; ++t)
#pragma unroll
      for (int r = 0; r < 16; ++r) st[t][r] = negm;
    __builtin_amdgcn_s_setprio(1);
#pragma unroll
    for (int kt = 0; kt < 4; ++kt) {
#pragma unroll
      for (int t = 0; t < 2; ++t) {
        half8 kf = *(const half8*)&Kb[(t * 32 + l31) * KSTR + kt * 16 + b8];
        st[t] = __builtin_amdgcn_mfma_f32_32x32x16_f16(kf, qf[kt], st[t], 0, 0, 0);
      }
    }
    __builtin_amdgcn_s_setprio(0);

    // ---- deferred online softmax: max check only; rare rescale path ----
    float mx;
    {
      float a[16];
#pragma unroll
      for (int r = 0; r < 16; ++r) a[r] = fmaxf(st[0][r], st[1][r]);
      float c0 = fmaxf(fmaxf(a[0],  a[1]),  fmaxf(a[2],  a[3]));
      float c1 = fmaxf(fmaxf(a[4],  a[5]),  fmaxf(a[6],  a[7]));
      float c2 = fmaxf(fmaxf(a[8],  a[9]),  fmaxf(a[10], a[11]));
      float c3 = fmaxf(fmaxf(a[12], a[13]), fmaxf(a[14], a[15]));
      mx = fmaxf(fmaxf(c0, c1), fmaxf(c2, c3));
    }
    mx = fmaxf(mx, __shfl_xor(mx, 32, 64));   // cross-half: full row max

    if (__any(mx > RESCALE_THR)) {            // rare: max grew meaningfully
      float d  = fmaxf(mx, 0.f);
      m_run += d;
      float al = EXP2F(-d);
#pragma unroll
      for (int t = 0; t < 2; ++t)
#pragma unroll
        for (int r = 0; r < 16; ++r) st[t][r] -= d;
#pragma unroll
      for (int r = 0; r < 16; ++r) {
        int row = (r & 3) + 8 * (r >> 2) + 4 * hb;
        float ar = __shfl(al, row, 64);
        accO[0][r] *= ar;
        accO[1][r] *= ar;
        accL[r]    *= ar;
      }
    }

#pragma unroll
    for (int t = 0; t < 2; ++t)
#pragma unroll
      for (int r = 0; r < 16; ++r)
        st[t][r] = EXP2F(st[t][r]);           // P, bounded by 2^THR

    WGBAR();                         // B2: V^T visible; QK reads of Kb drained

    // ---- P·V (+ row-sum into accL via ones MFMA) ----
    __builtin_amdgcn_s_setprio(1);
#pragma unroll
    for (int t = 0; t < 2; ++t) {
      unsigned P01 = pk2(st[t][0],  st[t][1]);
      unsigned P23 = pk2(st[t][2],  st[t][3]);
      unsigned P45 = pk2(st[t][4],  st[t][5]);
      unsigned P67 = pk2(st[t][6],  st[t][7]);
      unsigned P89 = pk2(st[t][8],  st[t][9]);
      unsigned PAB = pk2(st[t][10], st[t][11]);
      unsigned PCD = pk2(st[t][12], st[t][13]);
      unsigned PEF = pk2(st[t][14], st[t][15]);
      F8U fe, fo;
#if HAVE_PL32
      pl32(P01, P45); fe.u[0] = P01; fe.u[2] = P45;
      pl32(P23, P67); fe.u[1] = P23; fe.u[3] = P67;
      pl32(P89, PCD); fo.u[0] = P89; fo.u[2] = PCD;
      pl32(PAB, PEF); fo.u[1] = PAB; fo.u[3] = PEF;
#else
      unsigned x01 = __shfl_xor(P01, 32, 64), x23 = __shfl_xor(P23, 32, 64);
      unsigned x45 = __shfl_xor(P45, 32, 64), x67 = __shfl_xor(P67, 32, 64);
      unsigned x89 = __shfl_xor(P89, 32, 64), xAB = __shfl_xor(PAB, 32, 64);
      unsigned xCD = __shfl_xor(PCD, 32, 64), xEF = __shfl_xor(PEF, 32, 64);
      fe.u = uint4v{hb ? x45 : P01, hb ? x67 : P23, hb ? P45 : x01, hb ? P67 : x23};
      fo.u = uint4v{hb ? xCD : P89, hb ? xEF : PAB, hb ? PCD : x89, hb ? PEF : xAB};
#endif
      accL = __builtin_amdgcn_mfma_f32_32x32x16_f16(fe.h, ones, accL, 0, 0, 0);
      accL = __builtin_amdgcn_mfma_f32_32x32x16_f16(fo.h, ones, accL, 0, 0, 0);
#pragma unroll
      for (int ds = 0; ds < 2; ++ds) {
        half8 vf0 = *(const half8*)&Vb[(ds * 32 + l31) * VSTR + (2 * t) * 16 + b8];
        accO[ds] = __builtin_amdgcn_mfma_f32_32x32x16_f16(fe.h, vf0, accO[ds], 0, 0, 0);
        half8 vf1 = *(const half8*)&Vb[(ds * 32 + l31) * VSTR + (2 * t + 1) * 16 + b8];
        accO[ds] = __builtin_amdgcn_mfma_f32_32x32x16_f16(fo.h, vf1, accO[ds], 0, 0, 0);
      }
    }
    __builtin_amdgcn_s_setprio(0);
    buf ^= 1;
  }

  const int rowbase = batch * SQL + qb * BM + wv * 32;
  if (NSPLIT == 1) {
    float* op = out + (size_t)rowbase * DH;
#pragma unroll
    for (int r = 0; r < 16; ++r) {
      int row = (r & 3) + 8 * (r >> 2) + 4 * hb;
      float lr = 1.0f / accL[r];              // all lanes hold row sums
      op[(size_t)row * DH + l31]      = accO[0][r] * lr;
      op[(size_t)row * DH + 32 + l31] = accO[1][r] * lr;
    }
  } else {
    // unnormalized partials + (m,l) per q-row
    float* po = pO + ((size_t)split * NBATCH * SQL + rowbase) * DH;
#pragma unroll
    for (int r = 0; r < 16; ++r) {
      int row = (r & 3) + 8 * (r >> 2) + 4 * hb;
      po[(size_t)row * DH + l31]      = accO[0][r];
      po[(size_t)row * DH + 32 + l31] = accO[1][r];
    }
    if (hb == 0)
      pM[(size_t)split * NBATCH * SQL + rowbase + l31] = m_run;
    if (l31 == 0) {                           // lanes 0 and 32 cover all 32 rows
#pragma unroll
      for (int r = 0; r < 16; ++r) {
        int row = (r & 3) + 8 * (r >> 2) + 4 * hb;
        pL[(size_t)split * NBATCH * SQL + rowbase + row] = accL[r];
      }
    }
  }
}

__global__ __launch_bounds__(256)
void merge3(const float* __restrict__ pO, const float* __restrict__ pM,
            const float* __restrict__ pL, float* __restrict__ out)
{
  const int i4   = blockIdx.x * 256 + threadIdx.x;    // float4 index
  const int rowg = i4 >> 4;                           // (i4*4)>>6
  const size_t PLANE4 = (size_t)NBATCH * SQL * DH / 4;  // 524288
  const int    RPL    = NBATCH * SQL;                   // 32768
  float m0 = pM[rowg], m1 = pM[RPL + rowg], m2 = pM[2 * RPL + rowg];
  float mx = fmaxf(fmaxf(m0, m1), m2);
  float w0 = EXP2F(m0 - mx), w1 = EXP2F(m1 - mx), w2 = EXP2F(m2 - mx);
  float l = w0 * pL[rowg] + w1 * pL[RPL + rowg] + w2 * pL[2 * RPL + rowg];
  float li = 1.0f / l;
  const floatx4* p0 = (const floatx4*)pO;
  floatx4 o0 = p0[i4], o1 = p0[PLANE4 + i4], o2 = p0[2 * PLANE4 + i4];
  floatx4 o;
#pragma unroll
  for (int j = 0; j < 4; ++j)
    o[j] = (w0 * o0[j] + w1 * o1[j] + w2 * o2[j]) * li;
  ((floatx4*)out)[i4] = o;
}

extern "C" void kernel_launch(void* const* d_in, const int* in_sizes, int n_in,
                              void* d_out, int out_size, void* d_ws, size_t ws_size,
                              hipStream_t stream) {
  (void)in_sizes; (void)n_in; (void)out_size;
  const float* q = (const float*)d_in[0];
  const float* k = (const float*)d_in[1];
  const float* v = (const float*)d_in[2];
  float* out = (float*)d_out;

  const size_t PLANE = (size_t)NBATCH * SQL * DH;              // floats per split plane
  const size_t RPL   = (size_t)NBATCH * SQL;                   // rows per split
  const size_t need  = (3 * PLANE + 6 * RPL) * sizeof(float);  // ~26 MB

  if (ws_size >= need) {
    float* pO = (float*)d_ws;
    float* pM = pO + 3 * PLANE;
    float* pL = pM + 3 * RPL;
    ring_attn<NSPL><<<dim3(768), dim3(256), 0, stream>>>(q, k, v, nullptr, pO, pM, pL);
    merge3<<<dim3((NBATCH * SQL * DH) / 1024), dim3(256), 0, stream>>>(pO, pM, pL, out);
  } else {
    ring_attn<1><<<dim3(256), dim3(256), 0, stream>>>(q, k, v, out, nullptr, nullptr, nullptr);
  }
}